// Round 5
// baseline (597.373 us; speedup 1.0000x reference)
//
#include <hip/hip_runtime.h>
#include <hip/hip_bf16.h>

#define N_ROWS 131072
#define DIM 256
#define K_CODES 1024
#define BLK_ROWS 256        // 4 waves x 64 rows
#define NCHUNK 32           // 32 codes per chunk
#define FRAG_SH 512         // shorts per fragment (64 lanes x 8 bf16)
#define CHUNK_SH (32 * FRAG_SH)   // 32 frags/chunk: [0..16)=GEMM1 A, [16..32)=GEMM2 B

typedef __attribute__((ext_vector_type(8))) short bf16x8;
typedef __attribute__((ext_vector_type(16))) float f32x16;
typedef __attribute__((ext_vector_type(4))) unsigned int u32x4;

__device__ __forceinline__ short f2bf(float x) {
    unsigned u = __float_as_uint(x);
    u += 0x7fff + ((u >> 16) & 1);   // RNE
    return (short)(u >> 16);
}
// packed fp32x2 -> bf16x2 (v_cvt_pk_bf16_f32 on gfx950)
__device__ __forceinline__ unsigned pk2(float x, float y) {
    union { __hip_bfloat162 h; unsigned u; } cv;
    cv.h = __float22bfloat162_rn(float2{x, y});
    return cv.u;
}
__device__ __forceinline__ bf16x8 pk8(float4 v0, float4 v1) {
    union { bf16x8 b; u32x4 u; } cv;
    cv.u[0] = pk2(v0.x, v0.y); cv.u[1] = pk2(v0.z, v0.w);
    cv.u[2] = pk2(v1.x, v1.y); cv.u[3] = pk2(v1.z, v1.w);
    return cv.b;
}

typedef const __attribute__((address_space(1))) unsigned int* gas1_t;
typedef __attribute__((address_space(3))) unsigned int* las3_t;
__device__ __forceinline__ void gload16(const short* g, short* l) {
    // per-lane global addr (contiguous 16B/lane); wave-uniform LDS base + lane*16
    __builtin_amdgcn_global_load_lds((gas1_t)(const void*)g, (las3_t)(void*)l, 16, 0, 0);
}

// ---------------- prep: codebook -> fragment-order bf16 (one block per 32-code chunk)
// (unchanged from round 4 — verified correct)
__global__ void prep_kernel(const float* __restrict__ cb,
                            short* __restrict__ bg) {
    __shared__ __align__(16) float tile[32 * 264];   // [code][d] fp32, stride 264
    __shared__ float en2s[32];
    const int tid = threadIdx.x;
    const int w = tid >> 6, l = tid & 63, hf = l >> 5, c31 = l & 31;
    const int ch = blockIdx.x, cb0 = ch * 32;

#pragma unroll
    for (int it = 0; it < 8; ++it) {
        int idx = it * 256 + tid;          // float4 index
        int r = idx >> 6, c = (idx & 63) * 4;
        *(float4*)&tile[r * 264 + c] = *(const float4*)&cb[(size_t)(cb0 + r) * DIM + c];
    }
    __syncthreads();

    {   // en2[c] = exp(-||e_c||^2), 8 threads per code
        int c = tid >> 3, part = tid & 7;
        float s = 0.f;
#pragma unroll
        for (int j = 0; j < 32; ++j) {
            float v = tile[c * 264 + part * 32 + j];
            s += v * v;
        }
        s += __shfl_xor(s, 1, 64);
        s += __shfl_xor(s, 2, 64);
        s += __shfl_xor(s, 4, 64);
        if (part == 0) en2s[c] = __expf(-s);
    }
    __syncthreads();

    // GEMM1 A-frags (f = t = 0..15): lane holds E[cb0 + c31][t*16 + hf*8 + j]
#pragma unroll
    for (int i = 0; i < 4; ++i) {
        int f = i * 4 + w;
        const float* src = &tile[c31 * 264 + f * 16 + hf * 8];
        *(bf16x8*)&bg[ch * CHUNK_SH + f * FRAG_SH + l * 8] =
            pk8(*(const float4*)src, *(const float4*)(src + 4));
    }
    // GEMM2 B-frags (f = 16 + n2*2 + t2), en2-folded, kappa code order:
    // slot (hf, j) holds code (t2*2 + (j>>2))*8 + 4*hf + (j&3), matching P's A-register order
#pragma unroll
    for (int i = 0; i < 4; ++i) {
        int g = i * 4 + w;
        int n2 = g >> 1, t2 = g & 1;
        int d = n2 * 32 + c31;
        bf16x8 v;
#pragma unroll
        for (int j = 0; j < 8; ++j) {
            int c2 = (t2 * 2 + (j >> 2)) * 8 + 4 * hf + (j & 3);
            v[j] = f2bf(tile[c2 * 264 + d] * en2s[c2]);
        }
        *(bf16x8*)&bg[ch * CHUNK_SH + (16 + g) * FRAG_SH + l * 8] = v;
    }
}

// ---------------- main fused kernel: 64 rows/wave, 1 wave/SIMD by design ----------------
__global__ __launch_bounds__(256, 1)
void svq_kernel(const float* __restrict__ z,
                const short* __restrict__ bg,
                float* __restrict__ out,
                float* __restrict__ loss) {
    __shared__ __align__(16) short lds_b[2 * CHUNK_SH];  // 2 x 32 KB double buffer

    const int tid = threadIdx.x;
    const int w = tid >> 6, l = tid & 63, hf = l >> 5, c31 = l & 31;
    const int rowbase = blockIdx.x * BLK_ROWS + w * 64;   // this wave: rows [rowbase, rowbase+64)

    // z fragments, two 32-row m-tiles. Lane holds z[row][t*16 + hf*8 + j];
    // this register layout doubles as the MFMA B-operand for GEMM1.
    bf16x8 za0[16], za1[16];
    float sz2 = 0.f;   // exact fp32 sum of z^2 over this lane's 256 elements
    {
        const float* zr0 = z + (size_t)(rowbase + c31) * DIM + hf * 8;
        const float* zr1 = zr0 + (size_t)32 * DIM;
#pragma unroll
        for (int t = 0; t < 16; ++t) {
            float4 a0 = *(const float4*)(zr0 + t * 16);
            float4 a1 = *(const float4*)(zr0 + t * 16 + 4);
            float4 b0 = *(const float4*)(zr1 + t * 16);
            float4 b1 = *(const float4*)(zr1 + t * 16 + 4);
            sz2 += a0.x*a0.x + a0.y*a0.y + a0.z*a0.z + a0.w*a0.w
                 + a1.x*a1.x + a1.y*a1.y + a1.z*a1.z + a1.w*a1.w
                 + b0.x*b0.x + b0.y*b0.y + b0.z*b0.z + b0.w*b0.w
                 + b1.x*b1.x + b1.y*b1.y + b1.z*b1.z + b1.w*b1.w;
            za0[t] = pk8(a0, a1);
            za1[t] = pk8(b0, b1);
        }
    }

    f32x16 o0[8], o1[8];
#pragma unroll
    for (int i = 0; i < 8; ++i) {
        o0[i] = (f32x16){0.f,0.f,0.f,0.f,0.f,0.f,0.f,0.f,0.f,0.f,0.f,0.f,0.f,0.f,0.f,0.f};
        o1[i] = (f32x16){0.f,0.f,0.f,0.f,0.f,0.f,0.f,0.f,0.f,0.f,0.f,0.f,0.f,0.f,0.f,0.f};
    }
    float rs0 = 0.f, rs1 = 0.f;   // softmax denominators (per lane's row)
    float q0 = 0.f, q1 = 0.f;     // sum p*s -> zs.z for loss (no z re-read)

    // prologue: stage chunk 0 into buffer 0
    {
        const short* sg = bg + l * 8;
#pragma unroll
        for (int i = 0; i < 8; ++i) {
            int f = i * 4 + w;
            gload16(sg + f * FRAG_SH, &lds_b[f * FRAG_SH]);
        }
    }

    for (int ch = 0; ch < NCHUNK; ++ch) {
        // drains chunk-ch staging and makes buffer (ch+1)&1 safe to overwrite
        __syncthreads();
        if (ch + 1 < NCHUNK) {
            const short* sg = bg + (ch + 1) * CHUNK_SH + l * 8;
            short* lbase = &lds_b[((ch + 1) & 1) * CHUNK_SH];
#pragma unroll
            for (int i = 0; i < 8; ++i) {
                int f = i * 4 + w;
                gload16(sg + f * FRAG_SH, lbase + f * FRAG_SH);
            }
        }

        const short* lb = &lds_b[(ch & 1) * CHUNK_SH + l * 8];

        // GEMM1 (transposed): S^T[32 codes x 64 rows] = E . Z^T — A-frag shared by both m-tiles
        f32x16 s0 = (f32x16){0.f,0.f,0.f,0.f,0.f,0.f,0.f,0.f,0.f,0.f,0.f,0.f,0.f,0.f,0.f,0.f};
        f32x16 s1 = (f32x16){0.f,0.f,0.f,0.f,0.f,0.f,0.f,0.f,0.f,0.f,0.f,0.f,0.f,0.f,0.f,0.f};
#pragma unroll
        for (int t = 0; t < 16; ++t) {
            bf16x8 a = *(const bf16x8*)(lb + t * FRAG_SH);
            s0 = __builtin_amdgcn_mfma_f32_32x32x16_bf16(a, za0[t], s0, 0, 0, 0);
            s1 = __builtin_amdgcn_mfma_f32_32x32x16_bf16(a, za1[t], s1, 0, 0, 0);
        }

        // softmax numerators -> GEMM2 A-frags (pk cvt), running denominators
        bf16x8 a2_00, a2_01, a2_10, a2_11;
        {
            float p[16];
#pragma unroll
            for (int reg = 0; reg < 16; ++reg) {
                float sv = s0[reg];
                float pv = exp2f(sv * 2.8853900818f);   // exp(2 z.e)
                rs0 += pv; q0 += pv * sv; p[reg] = pv;
            }
            union { bf16x8 b; u32x4 u; } c0, c1;
#pragma unroll
            for (int i = 0; i < 4; ++i) {
                c0.u[i] = pk2(p[2*i], p[2*i+1]);
                c1.u[i] = pk2(p[8+2*i], p[9+2*i]);
            }
            a2_00 = c0.b; a2_01 = c1.b;
#pragma unroll
            for (int reg = 0; reg < 16; ++reg) {
                float sv = s1[reg];
                float pv = exp2f(sv * 2.8853900818f);
                rs1 += pv; q1 += pv * sv; p[reg] = pv;
            }
#pragma unroll
            for (int i = 0; i < 4; ++i) {
                c0.u[i] = pk2(p[2*i], p[2*i+1]);
                c1.u[i] = pk2(p[8+2*i], p[9+2*i]);
            }
            a2_10 = c0.b; a2_11 = c1.b;
        }

        // GEMM2: o += P . E' — B-frag shared by both m-tiles
#pragma unroll
        for (int n2 = 0; n2 < 8; ++n2) {
            bf16x8 b0 = *(const bf16x8*)(lb + (16 + n2 * 2) * FRAG_SH);
            o0[n2] = __builtin_amdgcn_mfma_f32_32x32x16_bf16(a2_00, b0, o0[n2], 0, 0, 0);
            o1[n2] = __builtin_amdgcn_mfma_f32_32x32x16_bf16(a2_10, b0, o1[n2], 0, 0, 0);
            bf16x8 b1 = *(const bf16x8*)(lb + (16 + n2 * 2 + 1) * FRAG_SH);
            o0[n2] = __builtin_amdgcn_mfma_f32_32x32x16_bf16(a2_01, b1, o0[n2], 0, 0, 0);
            o1[n2] = __builtin_amdgcn_mfma_f32_32x32x16_bf16(a2_11, b1, o1[n2], 0, 0, 0);
        }
    }

    // combine hf-halves of each row's partial sums
    float rst0 = rs0 + __shfl_xor(rs0, 32, 64);
    float rst1 = rs1 + __shfl_xor(rs1, 32, 64);
    float qt0  = q0 + __shfl_xor(q0, 32, 64);
    float qt1  = q1 + __shfl_xor(q1, 32, 64);
    float inv0 = 1.f / rst0, inv1 = 1.f / rst1;

    // broadcast inv to the C-layout rows this lane stores
    float invr0[16], invr1[16];
#pragma unroll
    for (int reg = 0; reg < 16; ++reg) {
        int r = (reg & 3) + 8 * (reg >> 2) + 4 * hf;
        invr0[reg] = __shfl(inv0, r, 64);
        invr1[reg] = __shfl(inv1, r, 64);
    }

    // epilogue: normalize, store, accumulate loss terms
    float zs2 = 0.f;
    const size_t ob0 = (size_t)rowbase * DIM;
    const size_t ob1 = ob0 + (size_t)32 * DIM;
#pragma unroll
    for (int n2 = 0; n2 < 8; ++n2) {
#pragma unroll
        for (int reg = 0; reg < 16; ++reg) {
            int r = (reg & 3) + 8 * (reg >> 2) + 4 * hf;
            float v0 = o0[n2][reg] * invr0[reg];
            float v1 = o1[n2][reg] * invr1[reg];
            out[ob0 + (size_t)r * DIM + n2 * 32 + c31] = v0;
            out[ob1 + (size_t)r * DIM + n2 * 32 + c31] = v1;
            zs2 += v0 * v0 + v1 * v1;
        }
    }

    // loss = mean(z^2) - 2*mean(zs.z) + mean(zs^2); zs.z per row = qt * inv
    float lacc = sz2 + zs2;
    if (hf == 0) lacc -= 2.f * (qt0 * inv0 + qt1 * inv1);
#pragma unroll
    for (int off = 32; off > 0; off >>= 1) lacc += __shfl_xor(lacc, off, 64);
    if (l == 0) atomicAdd(loss, lacc * (1.f / ((float)N_ROWS * (float)DIM)));
}

extern "C" void kernel_launch(void* const* d_in, const int* in_sizes, int n_in,
                              void* d_out, int out_size, void* d_ws, size_t ws_size,
                              hipStream_t stream) {
    const float* z = (const float*)d_in[0];
    const float* cb = (const float*)d_in[1];
    float* out = (float*)d_out;

    short* bg = (short*)d_ws;    // 32 chunks * 16384 shorts = 1 MB

    float* loss = out + (size_t)N_ROWS * DIM;
    hipMemsetAsync((void*)loss, 0, sizeof(float), stream);

    prep_kernel<<<dim3(NCHUNK), dim3(256), 0, stream>>>(cb, bg);
    svq_kernel<<<dim3(N_ROWS / BLK_ROWS), dim3(256), 0, stream>>>(
        z, bg, out, loss);
}